// Round 2
// baseline (278.580 us; speedup 1.0000x reference)
//
#include <hip/hip_runtime.h>

#define B_ 4
#define C_ 512
#define H_ 64
#define W_ 208
#define HID_ 512
#define NREG_ 4
#define DS_ 16

// ws layout: tmp [B*NREG*HID_] fp32 @0 (32KB) | swl [B*W] int @32KB
// No memset needed: tmp and swl are fully overwritten each launch.

// Blocks 0..31: tmp[b,r,d0+dd] = sum_{h=0..511} tf[r,b,h]*Wv[r,h,d0+dd]
//               (r = blk>>3, d0 = (blk&7)*64; full h-sum in one block -> no atomics)
// Blocks 32..35: parallel stable counting sort of column labels for b = blk-32
__global__ __launch_bounds__(256) void prep_kernel(
    const float* __restrict__ tf, const float* __restrict__ Wv,
    const int* __restrict__ mask, float* __restrict__ tmp, int* __restrict__ swl) {
  int blk = blockIdx.x, tid = threadIdx.x;
  if (blk < 32) {
    int r = blk >> 3;
    int d0 = (blk & 7) * 64;
    int g = tid >> 6, dd = tid & 63;
    __shared__ float tf_s[B_ * HID_];
    __shared__ float red[4][B_][64];
#pragma unroll
    for (int k = 0; k < 8; ++k) {
      int idx = k * 256 + tid;
      tf_s[idx] = tf[r * (B_ * HID_) + idx];
    }
    __syncthreads();
    float acc[B_] = {};
#pragma unroll 4
    for (int hh = g * 128; hh < g * 128 + 128; ++hh) {
      float w = Wv[(size_t)(r * HID_ + hh) * HID_ + d0 + dd];
#pragma unroll
      for (int b = 0; b < B_; ++b) acc[b] += tf_s[b * HID_ + hh] * w;
    }
#pragma unroll
    for (int b = 0; b < B_; ++b) red[g][b][dd] = acc[b];
    __syncthreads();
    {  // g now indexes b
      float s = red[0][g][dd] + red[1][g][dd] + red[2][g][dd] + red[3][g][dd];
      tmp[(g * NREG_ + r) * HID_ + d0 + dd] = s;
    }
  } else {
    int b = blk - 32;
    const size_t mb = (size_t)b * (H_ * DS_) * (W_ * DS_);
    int w = tid;
    int l = (w < W_) ? (mask[mb + (size_t)w * DS_] - 1) : -1;
    int wave = tid >> 6, lane = tid & 63;
    unsigned long long bal[NREG_];
    __shared__ int wcnt[4][NREG_];
#pragma unroll
    for (int r = 0; r < NREG_; ++r) bal[r] = __ballot(l == r);
    if (lane < NREG_) wcnt[wave][lane] = __popcll(bal[lane]);
    __syncthreads();
    if (w < W_) {
      int pos = 0;
#pragma unroll
      for (int q = 0; q < NREG_; ++q) {
        int tot = wcnt[0][q] + wcnt[1][q] + wcnt[2][q] + wcnt[3][q];
        if (q < l) pos += tot;
      }
#pragma unroll
      for (int v = 0; v < 4; ++v)
        if (v < wave) pos += wcnt[v][l];
      pos += __popcll(bal[l] & ((1ull << lane) - 1ull));
      swl[b * W_ + pos] = w | (l << 16);
    }
  }
}

// One block per (b,c) plane, grid 2048 = 8 blocks/CU x 256 CUs, fully resident.
// Prologue: computes its own delta[r] = sum_d tmp[b,r,d]*Wo[r,d,c] (prepB fused),
// overlapped with the tile-0 prefetch issued first.
// Main loop is software-pipelined: global loads for tile t+1 are issued into
// registers while tile t is gathered from LDS and stored coalesced, so the
// read and write streams interleave instead of the whole GPU oscillating
// between a read phase and a write phase.
#define RCH_ (W_ / 4)                 // 52 float4 per row
#define TROWS_ 16
#define TF4_ (TROWS_ * RCH_)          // 832 float4 per tile
#define NT_ (H_ / TROWS_)             // 4 tiles
__global__ __launch_bounds__(256, 8) void apply_kernel(
    const float* __restrict__ img, const float* __restrict__ tmp,
    const float* __restrict__ Wo, const int* __restrict__ swl,
    float* __restrict__ out) {
  int blk = blockIdx.x;
  int b = blk >> 9;          // / C_
  int c = blk & (C_ - 1);
  int tid = threadIdx.x;
  __shared__ int swl_s[W_];          // swl_s[pos] = src_col | (label<<16)
  __shared__ float dval[W_];         // dval[src_col] = delta to add
  __shared__ float dsel_s[NREG_];
  __shared__ float wred[4][NREG_];
  __shared__ float tile[TROWS_ * W_];

  const float4* srcv = (const float4*)(img + (size_t)blk * (H_ * W_));
  float4* dstv = (float4*)(out + (size_t)blk * (H_ * W_));

  // Issue tile-0 prefetch FIRST so its latency hides under the delta prologue.
  float4 pre[4];
#pragma unroll
  for (int g = 0; g < 4; ++g) {
    int ii = g * 256 + tid;
    if (ii < TF4_) pre[g] = srcv[ii];
  }
  if (tid < W_) swl_s[tid] = swl[b * W_ + tid];

  // delta[r] = sum_d tmp[b,r,d] * Wo[r,d,c]   (tmp, Wo are L2/L3-hot, 16 loads/thread)
  float acc[NREG_] = {};
#pragma unroll
  for (int k = 0; k < 2; ++k) {
    int d = k * 256 + tid;
#pragma unroll
    for (int r = 0; r < NREG_; ++r)
      acc[r] += tmp[(b * NREG_ + r) * HID_ + d] * Wo[(size_t)(r * HID_ + d) * C_ + c];
  }
#pragma unroll
  for (int r = 0; r < NREG_; ++r)
#pragma unroll
    for (int off = 32; off; off >>= 1) acc[r] += __shfl_down(acc[r], off);
  int wave = tid >> 6, lane = tid & 63;
  if (lane == 0) {
#pragma unroll
    for (int r = 0; r < NREG_; ++r) wred[wave][r] = acc[r];
  }
  __syncthreads();
  if (tid < NREG_)
    dsel_s[tid] = wred[0][tid] + wred[1][tid] + wred[2][tid] + wred[3][tid];
  __syncthreads();
  if (tid < W_) {
    int e = swl_s[tid];
    dval[e & 0xFFFF] = dsel_s[e >> 16];
  }
  __syncthreads();

  const float4* dval4 = (const float4*)dval;
  const int4* swl4 = (const int4*)swl_s;
  for (int t = 0; t < NT_; ++t) {
    // ---- ds_write tile t (+delta at source col), from prefetch regs ----
#pragma unroll
    for (int g = 0; g < 4; ++g) {
      int ii = g * 256 + tid;
      if (ii < TF4_) {
        int hl = ii / RCH_;
        int j = ii - hl * RCH_;
        float4 v = pre[g];
        float4 dv = dval4[j];
        float4 o;
        o.x = v.x + dv.x; o.y = v.y + dv.y; o.z = v.z + dv.z; o.w = v.w + dv.w;
        ((float4*)&tile[hl * W_])[j] = o;
      }
    }
    __syncthreads();
    // ---- issue prefetch for tile t+1 (overlaps gather+store below) ----
    if (t + 1 < NT_) {
#pragma unroll
      for (int g = 0; g < 4; ++g) {
        int ii = g * 256 + tid;
        if (ii < TF4_) pre[g] = srcv[(t + 1) * TF4_ + ii];
      }
    }
    // ---- gather tile t from LDS, coalesced float4 store ----
#pragma unroll
    for (int g = 0; g < 4; ++g) {
      int ii = g * 256 + tid;
      if (ii < TF4_) {
        int hl = ii / RCH_;
        int jo = ii - hl * RCH_;
        int4 sw = swl4[jo];
        const float* rowp = &tile[hl * W_];
        float4 o;
        o.x = rowp[sw.x & 0xFFFF];
        o.y = rowp[sw.y & 0xFFFF];
        o.z = rowp[sw.z & 0xFFFF];
        o.w = rowp[sw.w & 0xFFFF];
        dstv[t * TF4_ + ii] = o;
      }
    }
    __syncthreads();
  }
}

extern "C" void kernel_launch(void* const* d_in, const int* in_sizes, int n_in,
                              void* d_out, int out_size, void* d_ws, size_t ws_size,
                              hipStream_t stream) {
  const float* img  = (const float*)d_in[0];   // image_feature (B,C,H,W) fp32
  const float* tf   = (const float*)d_in[1];   // text_feat (NREG,B,HID) fp32
  const int*   mask = (const int*)d_in[2];     // text_mask (B,1,H*DS,W*DS) int32
  // d_in[3] = Wq (unused), d_in[4] = Wk (unused)
  const float* Wv   = (const float*)d_in[5];   // (NREG,HID,HID) fp32
  const float* Wo   = (const float*)d_in[6];   // (NREG,HID,C) fp32
  float* tmp = (float*)d_ws;
  int*   swl = (int*)((char*)d_ws + 32768);
  float* out = (float*)d_out;

  prep_kernel<<<36, 256, 0, stream>>>(tf, Wv, mask, tmp, swl);
  apply_kernel<<<B_ * C_, 256, 0, stream>>>(img, tmp, Wo, swl, out);
}

// Round 3
// 277.194 us; speedup vs baseline: 1.0050x; 1.0050x over previous
//
#include <hip/hip_runtime.h>

#define B_ 4
#define C_ 512
#define H_ 64
#define W_ 208
#define HID_ 512
#define NREG_ 4
#define DS_ 16

// ws layout: tmp [B*NREG*HID_] fp32 @0 (32KB) | delta [B*NREG*C_] fp32 @32KB | swl [B*W_] int @64KB
// No memset: tmp, delta, swl fully overwritten every launch (no atomics anywhere).

// prep1: blocks 0..63  : tmp[b,r,d0+dd] = sum_h tf[r,b,h]*Wv[r,h,d0+dd]
//                        r = blk>>4, d0 = (blk&15)*32; full-h sum in-block -> no atomics.
//        blocks 64..67 : parallel stable counting sort of column labels, b = blk-64.
__global__ __launch_bounds__(256) void prep1_kernel(
    const float* __restrict__ tf, const float* __restrict__ Wv,
    const int* __restrict__ mask, float* __restrict__ tmp, int* __restrict__ swl) {
  int blk = blockIdx.x, tid = threadIdx.x;
  if (blk < 64) {
    int r = blk >> 4;
    int d0 = (blk & 15) * 32;
    __shared__ float tf_s[B_ * HID_];
    __shared__ float red[8][B_][32];
#pragma unroll
    for (int k = 0; k < 8; ++k) {
      int idx = k * 256 + tid;
      tf_s[idx] = tf[r * (B_ * HID_) + idx];
    }
    __syncthreads();
    int hg = tid >> 5, dd = tid & 31;
    float acc[B_] = {};
#pragma unroll 4
    for (int q = 0; q < 64; ++q) {
      int hh = hg * 64 + q;
      float w = Wv[(size_t)(r * HID_ + hh) * HID_ + d0 + dd];
#pragma unroll
      for (int b = 0; b < B_; ++b) acc[b] += tf_s[b * HID_ + hh] * w;
    }
#pragma unroll
    for (int b = 0; b < B_; ++b) red[hg][b][dd] = acc[b];
    __syncthreads();
    if (tid < 128) {
      int b2 = tid >> 5, d2 = tid & 31;
      float s = 0.f;
#pragma unroll
      for (int q = 0; q < 8; ++q) s += red[q][b2][d2];
      tmp[(b2 * NREG_ + r) * HID_ + d0 + d2] = s;
    }
  } else {
    int b = blk - 64;
    const size_t mb = (size_t)b * (H_ * DS_) * (W_ * DS_);
    int w = tid;
    int l = (w < W_) ? (mask[mb + (size_t)w * DS_] - 1) : -1;
    int wave = tid >> 6, lane = tid & 63;
    unsigned long long bal[NREG_];
    __shared__ int wcnt[4][NREG_];
#pragma unroll
    for (int r = 0; r < NREG_; ++r) bal[r] = __ballot(l == r);
    if (lane < NREG_) wcnt[wave][lane] = __popcll(bal[lane]);
    __syncthreads();
    if (w < W_) {
      int pos = 0;
#pragma unroll
      for (int q = 0; q < NREG_; ++q) {
        int tot = wcnt[0][q] + wcnt[1][q] + wcnt[2][q] + wcnt[3][q];
        if (q < l) pos += tot;
      }
#pragma unroll
      for (int v = 0; v < 4; ++v)
        if (v < wave) pos += wcnt[v][l];
      pos += __popcll(bal[l] & ((1ull << lane) - 1ull));
      swl[b * W_ + pos] = w | (l << 16);
    }
  }
}

// prep2: delta[b,r,c0+cc] = sum_d tmp[b,r,d]*Wo[r,d,c0+cc]
//        32 blocks: r = blk>>3, c0 = (blk&7)*64; d split 4-way in-block, LDS reduce.
__global__ __launch_bounds__(256) void prep2_kernel(
    const float* __restrict__ tmp, const float* __restrict__ Wo,
    float* __restrict__ delta) {
  int blk = blockIdx.x, tid = threadIdx.x;
  int r = blk >> 3;
  int c0 = (blk & 7) * 64;
  __shared__ float tmp_s[B_ * HID_];
  __shared__ float red[4][B_][64];
#pragma unroll
  for (int k = 0; k < 8; ++k) {
    int idx = k * 256 + tid;
    int b = idx >> 9, d = idx & 511;
    tmp_s[idx] = tmp[(b * NREG_ + r) * HID_ + d];
  }
  __syncthreads();
  int dg = tid >> 6, cc = tid & 63;
  float acc[B_] = {};
#pragma unroll 4
  for (int q = 0; q < 128; ++q) {
    int d = dg * 128 + q;
    float w = Wo[(size_t)(r * HID_ + d) * C_ + c0 + cc];
#pragma unroll
    for (int b = 0; b < B_; ++b) acc[b] += tmp_s[b * HID_ + d] * w;
  }
#pragma unroll
  for (int b = 0; b < B_; ++b) red[dg][b][cc] = acc[b];
  __syncthreads();
  {  // dg slot reused as b
    float s = red[0][dg][cc] + red[1][dg][cc] + red[2][dg][cc] + red[3][dg][cc];
    delta[(dg * NREG_ + r) * C_ + c0 + cc] = s;
  }
}

// apply: one block per (b,c) plane; 4 waves; each wave owns 16 COMPLETE rows.
// Row permutation has no cross-wave sharing, so the steady state has ZERO
// __syncthreads: wave stages its 16x208 tile into wave-private LDS (writes and
// reads ordered by lgkmcnt within the wave), gathers, stores. Both global
// streams fully coalesced float4. Delta added at gather time from dquad
// (output-position-indexed). 16 rows = 832 f4 = exactly 13 f4/lane, and
// f4 index i satisfies i*4 == row*208 + col*4, so LDS addressing is linear.
// LDS ~55KB -> 2 blocks/CU; latency hidden by 13 loads in flight per lane,
// not by TLP.
#define RCH_ (W_ / 4)                 // 52 float4 per row
__global__ __launch_bounds__(256) void apply_kernel(
    const float* __restrict__ img, const float* __restrict__ delta,
    const int* __restrict__ swl, float* __restrict__ out) {
  int blk = blockIdx.x;
  int b = blk >> 9;          // / C_
  int c = blk & (C_ - 1);
  int tid = threadIdx.x;
  int wave = tid >> 6, lane = tid & 63;
  __shared__ int swl_s[W_];          // swl_s[pos] = src_col | (label<<16)
  __shared__ float dquad[W_];        // delta per OUTPUT position
  __shared__ float dsel_s[NREG_];
  __shared__ float tile[4][16 * W_]; // wave-private 16-row tiles

  const float4* srcv = (const float4*)(img + (size_t)blk * (H_ * W_));
  float4* dstv = (float4*)(out + (size_t)blk * (H_ * W_));
  int off = wave * (16 * RCH_);      // this wave's f4 offset (832*wave)

  // Issue all 13 tile loads first -> HBM latency hides under the prologue.
  float4 pre[13];
#pragma unroll
  for (int k = 0; k < 13; ++k) pre[k] = srcv[off + k * 64 + lane];

  if (tid < W_) swl_s[tid] = swl[b * W_ + tid];
  if (tid < NREG_) dsel_s[tid] = delta[(b * NREG_ + tid) * C_ + c];
  __syncthreads();
  if (tid < W_) dquad[tid] = dsel_s[swl_s[tid] >> 16];
  __syncthreads();

  float* mytile = &tile[wave][0];
  // ---- stage: linear f4 writes into wave-private LDS (conflict-free) ----
#pragma unroll
  for (int k = 0; k < 13; ++k) {
    ((float4*)mytile)[k * 64 + lane] = pre[k];
  }
  // ---- gather + add delta + coalesced store (same-wave lgkmcnt ordering) ----
  const int4* swl4 = (const int4*)swl_s;
  const float4* dq4 = (const float4*)dquad;
#pragma unroll
  for (int k = 0; k < 13; ++k) {
    int i = k * 64 + lane;
    int hl = i / RCH_;
    int jo = i - hl * RCH_;
    int4 sw = swl4[jo];
    float4 dq = dq4[jo];
    const float* rowp = mytile + hl * W_;
    float4 o;
    o.x = rowp[sw.x & 0xFFFF] + dq.x;
    o.y = rowp[sw.y & 0xFFFF] + dq.y;
    o.z = rowp[sw.z & 0xFFFF] + dq.z;
    o.w = rowp[sw.w & 0xFFFF] + dq.w;
    dstv[off + i] = o;
  }
}

extern "C" void kernel_launch(void* const* d_in, const int* in_sizes, int n_in,
                              void* d_out, int out_size, void* d_ws, size_t ws_size,
                              hipStream_t stream) {
  const float* img  = (const float*)d_in[0];   // image_feature (B,C,H,W) fp32
  const float* tf   = (const float*)d_in[1];   // text_feat (NREG,B,HID) fp32
  const int*   mask = (const int*)d_in[2];     // text_mask (B,1,H*DS,W*DS) int32
  // d_in[3] = Wq (unused), d_in[4] = Wk (unused)
  const float* Wv   = (const float*)d_in[5];   // (NREG,HID,HID) fp32
  const float* Wo   = (const float*)d_in[6];   // (NREG,HID,C) fp32
  float* tmp   = (float*)d_ws;
  float* delta = (float*)((char*)d_ws + 32768);
  int*   swl   = (int*)((char*)d_ws + 65536);
  float* out   = (float*)d_out;

  prep1_kernel<<<68, 256, 0, stream>>>(tf, Wv, mask, tmp, swl);
  prep2_kernel<<<32, 256, 0, stream>>>(tmp, Wo, delta);
  apply_kernel<<<B_ * C_, 256, 0, stream>>>(img, delta, swl, out);
}

// Round 5
// 260.995 us; speedup vs baseline: 1.0674x; 1.0621x over previous
//
#include <hip/hip_runtime.h>

#define B_ 4
#define C_ 512
#define H_ 64
#define W_ 208
#define HID_ 512
#define NREG_ 4
#define DS_ 16

typedef float f32x4 __attribute__((ext_vector_type(4)));
typedef int i32x4 __attribute__((ext_vector_type(4)));

// ws layout: tmp [B*NREG*HID_] fp32 @0 (32KB) | delta [B*NREG*C_] fp32 @32KB | swl [B*W_] int @64KB
// No memset: tmp, delta, swl fully overwritten every launch (no atomics anywhere).

// prep1: blocks 0..63  : tmp[b,r,d0+dd] = sum_h tf[r,b,h]*Wv[r,h,d0+dd]
//        blocks 64..67 : parallel stable counting sort of column labels, b = blk-64.
__global__ __launch_bounds__(256) void prep1_kernel(
    const float* __restrict__ tf, const float* __restrict__ Wv,
    const int* __restrict__ mask, float* __restrict__ tmp, int* __restrict__ swl) {
  int blk = blockIdx.x, tid = threadIdx.x;
  if (blk < 64) {
    int r = blk >> 4;
    int d0 = (blk & 15) * 32;
    __shared__ float tf_s[B_ * HID_];
    __shared__ float red[8][B_][32];
#pragma unroll
    for (int k = 0; k < 8; ++k) {
      int idx = k * 256 + tid;
      tf_s[idx] = tf[r * (B_ * HID_) + idx];
    }
    __syncthreads();
    int hg = tid >> 5, dd = tid & 31;
    float acc[B_] = {};
#pragma unroll 4
    for (int q = 0; q < 64; ++q) {
      int hh = hg * 64 + q;
      float w = Wv[(size_t)(r * HID_ + hh) * HID_ + d0 + dd];
#pragma unroll
      for (int b = 0; b < B_; ++b) acc[b] += tf_s[b * HID_ + hh] * w;
    }
#pragma unroll
    for (int b = 0; b < B_; ++b) red[hg][b][dd] = acc[b];
    __syncthreads();
    if (tid < 128) {
      int b2 = tid >> 5, d2 = tid & 31;
      float s = 0.f;
#pragma unroll
      for (int q = 0; q < 8; ++q) s += red[q][b2][d2];
      tmp[(b2 * NREG_ + r) * HID_ + d0 + d2] = s;
    }
  } else {
    int b = blk - 64;
    const size_t mb = (size_t)b * (H_ * DS_) * (W_ * DS_);
    int w = tid;
    int l = (w < W_) ? (mask[mb + (size_t)w * DS_] - 1) : -1;
    int wave = tid >> 6, lane = tid & 63;
    unsigned long long bal[NREG_];
    __shared__ int wcnt[4][NREG_];
#pragma unroll
    for (int r = 0; r < NREG_; ++r) bal[r] = __ballot(l == r);
    if (lane < NREG_) wcnt[wave][lane] = __popcll(bal[lane]);
    __syncthreads();
    if (w < W_) {
      int pos = 0;
#pragma unroll
      for (int q = 0; q < NREG_; ++q) {
        int tot = wcnt[0][q] + wcnt[1][q] + wcnt[2][q] + wcnt[3][q];
        if (q < l) pos += tot;
      }
#pragma unroll
      for (int v = 0; v < 4; ++v)
        if (v < wave) pos += wcnt[v][l];
      pos += __popcll(bal[l] & ((1ull << lane) - 1ull));
      swl[b * W_ + pos] = w | (l << 16);
    }
  }
}

// prep2: delta[b,r,c0+cc] = sum_d tmp[b,r,d]*Wo[r,d,c0+cc]; 32 blocks.
__global__ __launch_bounds__(256) void prep2_kernel(
    const float* __restrict__ tmp, const float* __restrict__ Wo,
    float* __restrict__ delta) {
  int blk = blockIdx.x, tid = threadIdx.x;
  int r = blk >> 3;
  int c0 = (blk & 7) * 64;
  __shared__ float tmp_s[B_ * HID_];
  __shared__ float red[4][B_][64];
#pragma unroll
  for (int k = 0; k < 8; ++k) {
    int idx = k * 256 + tid;
    int b = idx >> 9, d = idx & 511;
    tmp_s[idx] = tmp[(b * NREG_ + r) * HID_ + d];
  }
  __syncthreads();
  int dg = tid >> 6, cc = tid & 63;
  float acc[B_] = {};
#pragma unroll 4
  for (int q = 0; q < 128; ++q) {
    int d = dg * 128 + q;
    float w = Wo[(size_t)(r * HID_ + d) * C_ + c0 + cc];
#pragma unroll
    for (int b = 0; b < B_; ++b) acc[b] += tmp_s[b * HID_ + d] * w;
  }
#pragma unroll
  for (int b = 0; b < B_; ++b) red[dg][b][cc] = acc[b];
  __syncthreads();
  {  // dg slot reused as b
    float s = red[0][dg][cc] + red[1][dg][cc] + red[2][dg][cc] + red[3][dg][cc];
    delta[(dg * NREG_ + r) * C_ + c0 + cc] = s;
  }
}

// apply: one block per (b,c) plane; 4 waves; each wave owns 16 complete rows.
// Round-3 structure (barrier-free steady state, wave-private LDS tiles) but the
// global->LDS staging now uses global_load_lds width=16: ZERO staging VGPRs
// (round 3 spilled the 52-VGPR prefetch array -> exactly +106496 KB scratch
// writes). LDS dest is wave-uniform base + lane*16 == our linear tile layout.
// Manual hazard handling: counted s_waitcnt vmcnt(6) lets gather of rows 0..7
// start while rows 8..15 are still in flight; vmcnt(0) before the rest.
// Output stores are nontemporal: out is never re-read, keep img in L3.
#define RCH_ (W_ / 4)                 // 52 float4 per row
__device__ __forceinline__ void gload_lds16(const float* g, float* l) {
  __builtin_amdgcn_global_load_lds(
      (const __attribute__((address_space(1))) void*)g,
      (__attribute__((address_space(3))) void*)l, 16, 0, 0);
}
__global__ __launch_bounds__(256) void apply_kernel(
    const float* __restrict__ img, const float* __restrict__ delta,
    const int* __restrict__ swl, float* __restrict__ out) {
  int blk = blockIdx.x;
  int b = blk >> 9;          // / C_
  int c = blk & (C_ - 1);
  int tid = threadIdx.x;
  int wave = tid >> 6, lane = tid & 63;
  __shared__ int swl_s[W_];          // swl_s[pos] = src_col | (label<<16)
  __shared__ float dquad[W_];        // delta per OUTPUT position
  __shared__ float dsel_s[NREG_];
  __shared__ float tile[4][16 * W_]; // wave-private 16-row tiles

  const float* srcf = img + (size_t)blk * (H_ * W_);
  f32x4* dstv = (f32x4*)(out + (size_t)blk * (H_ * W_));
  int off = wave * (16 * RCH_);      // this wave's f4 offset (832*wave)
  float* mytile = &tile[wave][0];

  // ---- tables (small L2-hot loads; barriers before any tile load is issued,
  //      so the implicit vmcnt(0) drain in __syncthreads is free) ----
  if (tid < 52) ((i32x4*)swl_s)[tid] = ((const i32x4*)(swl + b * W_))[tid];
  if (tid < NREG_) dsel_s[tid] = delta[(b * NREG_ + tid) * C_ + c];
  __syncthreads();
  if (tid < W_) dquad[tid] = dsel_s[swl_s[tid] >> 16];
  __syncthreads();

  // ---- issue all 13 direct global->LDS loads (no VGPR round-trip) ----
#pragma unroll
  for (int k = 0; k < 13; ++k)
    gload_lds16(srcf + (size_t)(off + k * 64 + lane) * 4, mytile + k * 256);

  const i32x4* swl4 = (const i32x4*)swl_s;
  const f32x4* dq4 = (const f32x4*)dquad;
#define GATHER_CHUNK(k) {                               \
    int i = (k) * 64 + lane;                            \
    int hl = i / RCH_;                                  \
    int jo = i - hl * RCH_;                             \
    i32x4 sw = swl4[jo];                                \
    f32x4 dq = dq4[jo];                                 \
    const float* rowp = mytile + hl * W_;               \
    f32x4 o;                                            \
    o.x = rowp[sw.x & 0xFFFF] + dq.x;                   \
    o.y = rowp[sw.y & 0xFFFF] + dq.y;                   \
    o.z = rowp[sw.z & 0xFFFF] + dq.z;                   \
    o.w = rowp[sw.w & 0xFFFF] + dq.w;                   \
    __builtin_nontemporal_store(o, &dstv[off + i]);     \
  }
  // First 7 loads done -> rows 0..7 resident -> chunks 0..5 safe.
  asm volatile("s_waitcnt vmcnt(6)" ::: "memory");
#pragma unroll
  for (int k = 0; k < 6; ++k) GATHER_CHUNK(k);
  // Drain remaining loads (plus phase-1 stores; harmless).
  asm volatile("s_waitcnt vmcnt(0)" ::: "memory");
#pragma unroll
  for (int k = 6; k < 13; ++k) GATHER_CHUNK(k);
#undef GATHER_CHUNK
}

extern "C" void kernel_launch(void* const* d_in, const int* in_sizes, int n_in,
                              void* d_out, int out_size, void* d_ws, size_t ws_size,
                              hipStream_t stream) {
  const float* img  = (const float*)d_in[0];   // image_feature (B,C,H,W) fp32
  const float* tf   = (const float*)d_in[1];   // text_feat (NREG,B,HID) fp32
  const int*   mask = (const int*)d_in[2];     // text_mask (B,1,H*DS,W*DS) int32
  // d_in[3] = Wq (unused), d_in[4] = Wk (unused)
  const float* Wv   = (const float*)d_in[5];   // (NREG,HID,HID) fp32
  const float* Wo   = (const float*)d_in[6];   // (NREG,HID,C) fp32
  float* tmp   = (float*)d_ws;
  float* delta = (float*)((char*)d_ws + 32768);
  int*   swl   = (int*)((char*)d_ws + 65536);
  float* out   = (float*)d_out;

  prep1_kernel<<<68, 256, 0, stream>>>(tf, Wv, mask, tmp, swl);
  prep2_kernel<<<32, 256, 0, stream>>>(tmp, Wo, delta);
  apply_kernel<<<B_ * C_, 256, 0, stream>>>(img, delta, swl, out);
}